// Round 3
// baseline (82.158 us; speedup 1.0000x reference)
//
#include <hip/hip_runtime.h>
#include <math.h>

#define B 2
#define T 2048
#define D 512
#define KW 64
#define SCALE 0.044194173824159216f   // 1/sqrt(512)

typedef __attribute__((ext_vector_type(8))) short short8;   // 8 bf16 (4 VGPRs)
typedef __attribute__((ext_vector_type(4))) float f32x4;    // MFMA C/D

// float -> bf16 (RNE)
__device__ __forceinline__ ushort f2bf(float f) {
  union { float f; unsigned u; } v; v.f = f;
  unsigned r = v.u + 0x7fffu + ((v.u >> 16) & 1u);
  return (ushort)(r >> 16);
}

// tanh-form gelu (identical to the harness-verified 2-kernel version)
__device__ __forceinline__ float gelu_fast(float v) {
  float v2 = v * v;
  float u  = fmaf(v2 * v, 0.03567740814f, 0.7978845608f * v);
  float e  = __builtin_amdgcn_exp2f(2.885390082f * u);
  float r  = __builtin_amdgcn_rcpf(1.f + e);
  return fmaf(-v, r, v);
}

// ---------------------------------------------------------------------------
// Dual-layout 96 KiB LDS buffer (union via index functions):
//
// t-major (conv writes, energy reads): logical q_win[j][c], j in [0,96),
//   c in [0,512).  elem = j*512 + (c ^ ((j&7)<<3))
//   XOR on c-bits 3..5: every b128 row access spreads over 8 16B slots of
//   the 128B bank cycle (floor); b128 runs of 8 stay contiguous (c%8==0).
//
// c-major chunks (transpose writes, context reads): chunk k = j in [32k,+32),
//   overlaid on the SAME 32 KiB region as t-major rows [32k,+32):
//   elem = (j>>5)*16384 + c*32 + ((j&31) ^ (((c>>1)&3)<<3))
//   XOR on j-bits 3..4 by c-bits 1..2: b128 writes/reads at bank floor.
// ---------------------------------------------------------------------------
__device__ __forceinline__ int qt_off(int j, int c) {
  return j * 512 + (c ^ ((j & 7) << 3));
}
__device__ __forceinline__ int qc_off(int c, int j) {
  return (j >> 5) * 16384 + c * 32 + ((j & 31) ^ (((c >> 1) & 3) << 3));
}

// ---------------------------------------------------------------------------
// Fully fused: conv+gelu -> t-major LDS -> energy (verified MFMA frags) ->
// softmax -> in-place chunked transpose -> context (verified MFMA frags).
// 256 blocks (1/CU), 4 waves. No workspace, no tr_read, no inline asm.
// ---------------------------------------------------------------------------
__global__ __launch_bounds__(256, 1) void k_fused(
    const float* __restrict__ x, const float* __restrict__ w,
    const float* __restrict__ bias, const float* __restrict__ gate,
    float* __restrict__ out) {
  __shared__ alignas(16) ushort s_q[96 * 512];     // 96 KiB dual-layout
  __shared__ alignas(16) f32x4 s_E[4 * 5 * 64];    // 20 KiB, lane-major
  __shared__ ushort s_attn[4][16 * 96];            // 12 KiB

  int blk  = blockIdx.x;               // 256 blocks = B*T/16
  int b    = blk >> 7;
  int t0   = (blk & 127) << 4;
  int tid  = threadIdx.x;
  int wv   = tid >> 6;
  int lane = tid & 63;
  int n    = lane & 15;
  int quad = lane >> 4;

  // ---- phase 1: conv+gelu fill of the 96-row t-major window --------------
  // thread owns c-block c0 = lane*8 (fixed -> w/b in regs once);
  // j rows = wv + 4*it, it = 0..23.
  int c0 = lane * 8;
  float wf[24], bf[8];
#pragma unroll
  for (int v4 = 0; v4 < 6; ++v4)
    *(float4*)&wf[v4 * 4] = *(const float4*)(w + (size_t)c0 * 3 + v4 * 4);
#pragma unroll
  for (int v4 = 0; v4 < 2; ++v4)
    *(float4*)&bf[v4 * 4] = *(const float4*)(bias + c0 + v4 * 4);
  const float* xb = x + (size_t)b * T;

  for (int it = 0; it < 24; ++it) {
    int j  = wv + it * 4;              // wave-uniform row
    int tp = t0 - 64 + j;              // t' of this row
    bool inr = (unsigned)tp < (unsigned)T;
    float xm1 = ((unsigned)(tp - 1) < (unsigned)T) ? xb[tp - 1] : 0.f;
    float x0  = inr                    ? xb[tp]     : 0.f;
    float xp1 = ((unsigned)(tp + 1) < (unsigned)T) ? xb[tp + 1] : 0.f;
    short8 pk;
#pragma unroll
    for (int e = 0; e < 8; ++e) {
      float v = fmaf(xm1, wf[e * 3], fmaf(x0, wf[e * 3 + 1],
                fmaf(xp1, wf[e * 3 + 2], bf[e])));
      pk[e] = inr ? (short)f2bf(gelu_fast(v)) : (short)0;
    }
    *(short8*)&s_q[qt_off(j, c0)] = pk;
  }
  __syncthreads();

  // ---- phase 2: energy partial GEMM (wave wv owns c in [wv*128,+128)) ----
  // Fragment formulas byte-identical to the verified 2-kernel k_attn,
  // with global q rows replaced by t-major LDS rows (j = t' - t0 + 64).
  short8 afr[4], bfr[4][5];
#pragma unroll
  for (int i = 0; i < 4; ++i) {
    int cofs = (wv * 4 + i) * 32 + quad * 8;
    afr[i] = *(const short8*)&s_q[qt_off(64 + n, cofs)];        // t' = t0+n
#pragma unroll
    for (int jc = 0; jc < 5; ++jc)
      bfr[i][jc] = *(const short8*)&s_q[qt_off(1 + jc * 16 + n, cofs)];
  }

  f32x4 acc[5];
#pragma unroll
  for (int jc = 0; jc < 5; ++jc) acc[jc] = (f32x4){0.f, 0.f, 0.f, 0.f};
#pragma unroll
  for (int i = 0; i < 4; ++i)
#pragma unroll
    for (int jc = 0; jc < 5; ++jc)
      acc[jc] = __builtin_amdgcn_mfma_f32_16x16x32_bf16(afr[i], bfr[i][jc],
                                                        acc[jc], 0, 0, 0);

  // ---- cross-wave reduce: lane-major f32x4 slabs (b128 LDS ops) ----------
#pragma unroll
  for (int jc = 0; jc < 5; ++jc)
    s_E[(wv * 5 + jc) * 64 + lane] = acc[jc];
  __syncthreads();

#pragma unroll
  for (int ww = 0; ww < 4; ++ww) {
    if (ww == wv) continue;
#pragma unroll
    for (int jc = 0; jc < 5; ++jc) {
      f32x4 v = s_E[(ww * 5 + jc) * 64 + lane];
      acc[jc][0] += v[0]; acc[jc][1] += v[1];
      acc[jc][2] += v[2]; acc[jc][3] += v[3];
    }
  }

  // ---- band-masked softmax (redundant per wave), private A' copy ---------
  ushort* sa = s_attn[wv];
#pragma unroll
  for (int r = 0; r < 4; ++r) {
    int m = quad * 4 + r;
    float e[5];
    float mx = -1e30f;
#pragma unroll
    for (int jc = 0; jc < 5; ++jc) {
      int j = jc * 16 + n;
      bool valid = (j >= m) && (j <= m + (KW - 1));
      e[jc] = valid ? acc[jc][r] * SCALE : -1e30f;
      mx = fmaxf(mx, e[jc]);
    }
#pragma unroll
    for (int off = 1; off <= 8; off <<= 1) mx = fmaxf(mx, __shfl_xor(mx, off, 64));
    float p[5];
    float s = 0.f;
#pragma unroll
    for (int jc = 0; jc < 5; ++jc) {
      p[jc] = (e[jc] > -1e29f) ? __expf(e[jc] - mx) : 0.f;
      s += p[jc];
    }
#pragma unroll
    for (int off = 1; off <= 8; off <<= 1) s += __shfl_xor(s, off, 64);
    float inv = 1.f / s;
    // A' row m: col j+1 = attn (j' shift keeps B-frags aligned),
    // cols {0, 81..95} = 0
#pragma unroll
    for (int jc = 0; jc < 5; ++jc) {
      int j = jc * 16 + n;
      sa[m * 96 + j + 1] = f2bf(p[jc] * inv);
    }
    int jp = (n == 0) ? 0 : (80 + n);
    sa[m * 96 + jp] = 0;
  }
  // same-wave LDS write->read: ordered via lgkmcnt, no barrier needed
  short8 afr2[3];
#pragma unroll
  for (int ks = 0; ks < 3; ++ks)
    afr2[ks] = *(const short8*)(sa + n * 96 + ks * 32 + quad * 8);

  // ---- phase 3: in-place transpose, 3 chunks of 32 j-rows ----------------
  // Per chunk: all threads read their columns to regs, barrier, write the
  // c-major chunk over the same 32 KiB region, barrier.
  for (int k = 0; k < 3; ++k) {
    short8 tr[8];
#pragma unroll
    for (int g = 0; g < 8; ++g) {
      int c  = tid + ((g & 1) << 8);
      int j0 = (g >> 1) << 3;
#pragma unroll
      for (int e = 0; e < 8; ++e)
        tr[g][e] = (short)s_q[qt_off(k * 32 + j0 + e, c)];
    }
    __syncthreads();
#pragma unroll
    for (int g = 0; g < 8; ++g) {
      int c  = tid + ((g & 1) << 8);
      int j0 = (g >> 1) << 3;
      *(short8*)&s_q[qc_off(c, k * 32 + j0)] = tr[g];
    }
    __syncthreads();
  }

  // ---- phase 4: context GEMM (verified fragment formulas, c-major LDS) ---
  const float tg = tanhf(gate[0]);
#pragma unroll
  for (int ncl = 0; ncl < 8; ++ncl) {
    int c = (wv * 8 + ncl) * 16 + n;
    f32x4 co = (f32x4){0.f, 0.f, 0.f, 0.f};
#pragma unroll
    for (int ks = 0; ks < 3; ++ks) {
      short8 bfr2 = *(const short8*)&s_q[qc_off(c, ks * 32 + quad * 8)];
      co = __builtin_amdgcn_mfma_f32_16x16x32_bf16(afr2[ks], bfr2, co, 0, 0, 0);
    }
    f32x4 o;
    o[0] = co[0] * tg; o[1] = co[1] * tg; o[2] = co[2] * tg; o[3] = co[3] * tg;
    *(f32x4*)(out + ((size_t)b * D + c) * T + t0 + quad * 4) = o;
  }
}

// ---------------------------------------------------------------------------
extern "C" void kernel_launch(void* const* d_in, const int* in_sizes, int n_in,
                              void* d_out, int out_size, void* d_ws, size_t ws_size,
                              hipStream_t stream) {
  const float* x      = (const float*)d_in[0];   // (B,1,T)
  const float* conv_w = (const float*)d_in[1];   // (D,1,3)
  const float* conv_b = (const float*)d_in[2];   // (D,)
  const float* gate   = (const float*)d_in[3];   // scalar
  float* out = (float*)d_out;                    // (B,D,T)
  (void)d_ws; (void)ws_size;                     // workspace intentionally unused

  k_fused<<<B * T / 16, 256, 0, stream>>>(x, conv_w, conv_b, gate, out);
}

// Round 4
// 73.488 us; speedup vs baseline: 1.1180x; 1.1180x over previous
//
#include <hip/hip_runtime.h>
#include <math.h>

#define B 2
#define T 2048
#define D 512
#define KW 64
#define SCALE 0.044194173824159216f   // 1/sqrt(512)

// padded q layout: 64 zero rows in front, 16 behind (row = 64 + t)
#define RQ (64 + T + 16)

typedef __attribute__((ext_vector_type(8))) short short8;   // 8 bf16 (4 VGPRs)
typedef __attribute__((ext_vector_type(4))) float f32x4;    // MFMA C/D

// float -> bf16 (RNE)
__device__ __forceinline__ ushort f2bf(float f) {
  union { float f; unsigned u; } v; v.f = f;
  unsigned r = v.u + 0x7fffu + ((v.u >> 16) & 1u);
  return (ushort)(r >> 16);
}

// tanh-form gelu (identical to the harness-verified versions)
__device__ __forceinline__ float gelu_fast(float v) {
  float v2 = v * v;
  float u  = fmaf(v2 * v, 0.03567740814f, 0.7978845608f * v);
  float e  = __builtin_amdgcn_exp2f(2.885390082f * u);
  float r  = __builtin_amdgcn_rcpf(1.f + e);
  return fmaf(-v, r, v);
}

// async global->LDS, 16B per lane; LDS dest = wave-uniform base + lane*16
__device__ __forceinline__ void gload_lds16(const ushort* gsrc, ushort* lds_dst) {
  __builtin_amdgcn_global_load_lds(
      (const __attribute__((address_space(1))) unsigned*)gsrc,
      (__attribute__((address_space(3))) unsigned*)lds_dst, 16, 0, 0);
}

// ---------------------------------------------------------------------------
// K1: conv+gelu -> q (t-major, padded, bf16). XCD-matched mapping: blk&7 =
// xcd -> (b, 512-t range) identical to k_attn's consumer swizzle, so attn
// staging reads hit the local XCD's L2. Blocks 512..519 zero q's pad rows
// (ws re-poisoned every launch). No qT, no LDS: transpose happens in k_attn.
// ---------------------------------------------------------------------------
__global__ __launch_bounds__(256) void k_conv(
    const float* __restrict__ x, const float* __restrict__ w,
    const float* __restrict__ bias, ushort* __restrict__ q) {
  int blk = blockIdx.x;
  int tid = threadIdx.x;

  if (blk >= 512) {            // ---- pad zeroing: 10240 x 16B stores ----
    int ztid = (blk - 512) * 256 + tid;          // 0..2047
    const uint4 z = {0u, 0u, 0u, 0u};
    for (int task = ztid; task < 10240; task += 2048) {
      size_t e;
      if (task < 8192) {                         // q front: 64 rows x 512
        int b = task >> 12, i = task & 4095;
        e = (size_t)b * RQ * D + (size_t)i * 8;
      } else {                                   // q back: 16 rows x 512
        int idx = task - 8192;
        int b = idx >> 10, i = idx & 1023;
        e = (size_t)b * RQ * D + (size_t)(64 + T) * D + (size_t)i * 8;
      }
      *(uint4*)(q + e) = z;
    }
    return;
  }

  // XCD-matched tile mapping (verbatim from the 75.6us version)
  int xcd = blk & 7;
  int i   = blk >> 3;                  // 0..63 within xcd
  int b   = xcd >> 2;
  int t0  = (xcd & 3) * 512 + (i >> 3) * 64;
  int c0  = (i & 7) * 64;

  // thread = (lt = tid>>2, 16-c strip cb = (tid&3)*16)
  int lt = tid >> 2;
  int cb = (tid & 3) << 4;
  int t = t0 + lt;
  float xm1 = (t > 0)     ? x[b * T + t - 1] : 0.f;
  float x0  =               x[b * T + t];
  float xp1 = (t < T - 1) ? x[b * T + t + 1] : 0.f;

  // vectorized weight/bias loads: 48 w floats (16B-aligned) + 16 bias
  float wf[48], bf[16];
#pragma unroll
  for (int v4 = 0; v4 < 12; ++v4)
    *(float4*)&wf[v4 * 4] = *(const float4*)(w + (size_t)(c0 + cb) * 3 + v4 * 4);
#pragma unroll
  for (int v4 = 0; v4 < 4; ++v4)
    *(float4*)&bf[v4 * 4] = *(const float4*)(bias + c0 + cb + v4 * 4);

  short8 h0, h1;
#pragma unroll
  for (int e = 0; e < 16; ++e) {
    float v = fmaf(xm1, wf[e * 3], fmaf(x0, wf[e * 3 + 1],
              fmaf(xp1, wf[e * 3 + 2], bf[e])));
    float g = gelu_fast(v);
    if (e < 8) h0[e] = (short)f2bf(g); else h1[e - 8] = (short)f2bf(g);
  }
  ushort* qp = q + ((size_t)b * RQ + 64 + t) * D + c0 + cb;
  *(short8*)qp = h0;
  *(short8*)(qp + 8) = h1;
}

// ---------------------------------------------------------------------------
// Dual-layout 96 KiB LDS buffer (verified in round 3):
// t-major (staging writes, energy reads): elem = j*512 + (c ^ ((j&7)<<3))
// c-major chunks (transpose writes, context reads), chunk k = j in [32k,+32):
//   elem = (j>>5)*16384 + c*32 + ((j&31) ^ (((c>>1)&3)<<3))
// ---------------------------------------------------------------------------
__device__ __forceinline__ int qt_off(int j, int c) {
  return j * 512 + (c ^ ((j & 7) << 3));
}
__device__ __forceinline__ int qc_off(int c, int j) {
  return (j >> 5) * 16384 + c * 32 + ((j & 31) ^ (((c >> 1) & 3) << 3));
}

// ---------------------------------------------------------------------------
// K2: stage 96-row q window via global_load_lds (pre-swizzled source ->
// linear LDS dest lands in qt_off layout) -> energy (MFMA) -> softmax ->
// in-place chunked transpose -> context (MFMA) -> out.
// 256 blocks (1/CU), 4 waves. Phases 2-4 verbatim from the verified round-3
// kernel.
// ---------------------------------------------------------------------------
__global__ __launch_bounds__(256, 1) void k_attn(
    const ushort* __restrict__ q, const float* __restrict__ gate,
    float* __restrict__ out) {
  __shared__ alignas(16) ushort s_q[96 * 512];     // 96 KiB dual-layout
  __shared__ alignas(16) f32x4 s_E[4 * 5 * 64];    // 20 KiB, lane-major
  __shared__ ushort s_attn[4][16 * 96];            // 12 KiB

  int blk  = blockIdx.x;                 // 256 blocks = 1/CU
  int tile = (blk & 7) * 32 + (blk >> 3);   // XCD k -> contiguous 512-t range
  int b    = tile >> 7;
  int t0   = (tile & 127) << 4;
  int tid  = threadIdx.x;
  int wv   = tid >> 6;
  int lane = tid & 63;
  int n    = lane & 15;
  int quad = lane >> 4;

  float g0 = gate[0];                    // hoisted off the epilogue path

  // ---- phase 1: stage window rows j in [0,96): q row t0+j (padded) -------
  // One global_load_lds per row per wave: 64 lanes x 16B = 1KB = one row.
  // Source pre-swizzled by (lane ^ (j&7)) so linear LDS dest == qt_off.
  const ushort* qwin = q + ((size_t)b * RQ + t0) * D;
  for (int it = 0; it < 24; ++it) {
    int j = wv + it * 4;                 // wave-uniform row
    gload_lds16(qwin + (size_t)j * D + ((lane ^ (j & 7)) << 3),
                &s_q[j * 512]);
  }
  __syncthreads();

  // ---- phase 2: energy partial GEMM (wave wv owns c in [wv*128,+128)) ----
  short8 afr[4], bfr[4][5];
#pragma unroll
  for (int i = 0; i < 4; ++i) {
    int cofs = (wv * 4 + i) * 32 + quad * 8;
    afr[i] = *(const short8*)&s_q[qt_off(64 + n, cofs)];        // t' = t0+n
#pragma unroll
    for (int jc = 0; jc < 5; ++jc)
      bfr[i][jc] = *(const short8*)&s_q[qt_off(1 + jc * 16 + n, cofs)];
  }

  f32x4 acc[5];
#pragma unroll
  for (int jc = 0; jc < 5; ++jc) acc[jc] = (f32x4){0.f, 0.f, 0.f, 0.f};
#pragma unroll
  for (int i = 0; i < 4; ++i)
#pragma unroll
    for (int jc = 0; jc < 5; ++jc)
      acc[jc] = __builtin_amdgcn_mfma_f32_16x16x32_bf16(afr[i], bfr[i][jc],
                                                        acc[jc], 0, 0, 0);

  // ---- cross-wave reduce: lane-major f32x4 slabs (b128 LDS ops) ----------
#pragma unroll
  for (int jc = 0; jc < 5; ++jc)
    s_E[(wv * 5 + jc) * 64 + lane] = acc[jc];
  __syncthreads();

#pragma unroll
  for (int ww = 0; ww < 4; ++ww) {
    if (ww == wv) continue;
#pragma unroll
    for (int jc = 0; jc < 5; ++jc) {
      f32x4 v = s_E[(ww * 5 + jc) * 64 + lane];
      acc[jc][0] += v[0]; acc[jc][1] += v[1];
      acc[jc][2] += v[2]; acc[jc][3] += v[3];
    }
  }

  // ---- band-masked softmax (redundant per wave), private A' copy ---------
  ushort* sa = s_attn[wv];
#pragma unroll
  for (int r = 0; r < 4; ++r) {
    int m = quad * 4 + r;
    float e[5];
    float mx = -1e30f;
#pragma unroll
    for (int jc = 0; jc < 5; ++jc) {
      int j = jc * 16 + n;
      bool valid = (j >= m) && (j <= m + (KW - 1));
      e[jc] = valid ? acc[jc][r] * SCALE : -1e30f;
      mx = fmaxf(mx, e[jc]);
    }
#pragma unroll
    for (int off = 1; off <= 8; off <<= 1) mx = fmaxf(mx, __shfl_xor(mx, off, 64));
    float p[5];
    float s = 0.f;
#pragma unroll
    for (int jc = 0; jc < 5; ++jc) {
      p[jc] = (e[jc] > -1e29f) ? __expf(e[jc] - mx) : 0.f;
      s += p[jc];
    }
#pragma unroll
    for (int off = 1; off <= 8; off <<= 1) s += __shfl_xor(s, off, 64);
    float inv = 1.f / s;
    // A' row m: col j+1 = attn (j' shift keeps B-frags aligned),
    // cols {0, 81..95} = 0
#pragma unroll
    for (int jc = 0; jc < 5; ++jc) {
      int j = jc * 16 + n;
      sa[m * 96 + j + 1] = f2bf(p[jc] * inv);
    }
    int jp = (n == 0) ? 0 : (80 + n);
    sa[m * 96 + jp] = 0;
  }
  // same-wave LDS write->read: ordered via lgkmcnt, no barrier needed
  short8 afr2[3];
#pragma unroll
  for (int ks = 0; ks < 3; ++ks)
    afr2[ks] = *(const short8*)(sa + n * 96 + ks * 32 + quad * 8);

  // ---- phase 3: in-place transpose, 3 chunks of 32 j-rows ----------------
  for (int k = 0; k < 3; ++k) {
    short8 tr[8];
#pragma unroll
    for (int g = 0; g < 8; ++g) {
      int c  = tid + ((g & 1) << 8);
      int j0 = (g >> 1) << 3;
#pragma unroll
      for (int e = 0; e < 8; ++e)
        tr[g][e] = (short)s_q[qt_off(k * 32 + j0 + e, c)];
    }
    __syncthreads();
#pragma unroll
    for (int g = 0; g < 8; ++g) {
      int c  = tid + ((g & 1) << 8);
      int j0 = (g >> 1) << 3;
      *(short8*)&s_q[qc_off(c, k * 32 + j0)] = tr[g];
    }
    __syncthreads();
  }

  // ---- phase 4: context GEMM (c-major LDS) -------------------------------
  const float tg = tanhf(g0);
#pragma unroll
  for (int ncl = 0; ncl < 8; ++ncl) {
    int c = (wv * 8 + ncl) * 16 + n;
    f32x4 co = (f32x4){0.f, 0.f, 0.f, 0.f};
#pragma unroll
    for (int ks = 0; ks < 3; ++ks) {
      short8 bfr2 = *(const short8*)&s_q[qc_off(c, ks * 32 + quad * 8)];
      co = __builtin_amdgcn_mfma_f32_16x16x32_bf16(afr2[ks], bfr2, co, 0, 0, 0);
    }
    f32x4 o;
    o[0] = co[0] * tg; o[1] = co[1] * tg; o[2] = co[2] * tg; o[3] = co[3] * tg;
    *(f32x4*)(out + ((size_t)b * D + c) * T + t0 + quad * 4) = o;
  }
}

// ---------------------------------------------------------------------------
extern "C" void kernel_launch(void* const* d_in, const int* in_sizes, int n_in,
                              void* d_out, int out_size, void* d_ws, size_t ws_size,
                              hipStream_t stream) {
  const float* x      = (const float*)d_in[0];   // (B,1,T)
  const float* conv_w = (const float*)d_in[1];   // (D,1,3)
  const float* conv_b = (const float*)d_in[2];   // (D,)
  const float* gate   = (const float*)d_in[3];   // scalar
  float* out = (float*)d_out;                    // (B,D,T)

  ushort* q_ws = (ushort*)d_ws;                  // bf16 t-major padded, 4.36 MB

  k_conv<<<520, 256, 0, stream>>>(x, conv_w, conv_b, q_ws);
  k_attn<<<B * T / 16, 256, 0, stream>>>(q_ws, gate, out);
}